// Round 3
// baseline (449.959 us; speedup 1.0000x reference)
//
#include <hip/hip_runtime.h>
#include <math.h>

// Problem constants
#define Hh   4
#define Bb   8
#define Qq   64
#define Kk   256
#define Dd   256
#define Nn   (Bb * Qq)          // 512
#define GNf  16.0f
#define EPSf 1e-5f

#define SKV  776                // KVb row stride: [k(256)|v(256)|p(256)|r(4)|pad]
#define SCB  1032               // Cb  row stride: [q(256)|k(256)|v(256)|p(256)|r(4)|pad]
#define GRID 512

// ---------------------------------------------------------------------------
// Shared-memory union: one 22.8 KB block reused across phases.
struct MomS {
    float4 wm[Kk];            // router weights per t           4096 B
    float  Pt[4][16][68];     // per-wave 16t x 64c, padded     17408 B
    float  sbuf[4][16];       //                                256 B
    float  onorm[Dd];         //                                1024 B
};
struct GemmS { float As[16][136]; float Ws[16][136]; };   // 17408 B
struct RtrS  { float WrT[4][260]; };                      // 4160 B
union  AllS  { MomS m; GemmS g; RtrS r; };

// ---------------------------------------------------------------------------
__device__ __forceinline__ float wred(float x) {
#pragma unroll
    for (int off = 32; off > 0; off >>= 1)
        x += __shfl_xor(x, off, 64);
    return x;
}

// ---------------------------------------------------------------------------
// Software grid barrier: memset-zeroed counter in workspace, device-scope
// atomics (the documented cross-XCD mechanism). Release: per-thread
// __threadfence before arrive; acquire: atomic acquire loads + trailing
// __threadfence. All 512 blocks are co-resident by construction
// (__launch_bounds__(256,2) -> VGPR<=256 -> 2 blocks/CU; LDS 22.8KB).
__device__ __forceinline__ void gridbar(unsigned* cnt, unsigned nblk) {
    __threadfence();
    __syncthreads();
    if (threadIdx.x == 0) {
        __hip_atomic_fetch_add(cnt, 1u, __ATOMIC_ACQ_REL, __HIP_MEMORY_SCOPE_AGENT);
        while (__hip_atomic_load(cnt, __ATOMIC_ACQUIRE, __HIP_MEMORY_SCOPE_AGENT)
               < nblk)
            __builtin_amdgcn_s_sleep(1);
    }
    __syncthreads();
    __threadfence();
}

// ---------------------------------------------------------------------------
// 64x128 tile gemm (proven): As transposed pitch-68, Ws pitch-136,
// inner loop = 3 x ds_read_b128 + 32 fma. Global prefetch across k0.
__device__ void gemm64(GemmS& g, const float* __restrict__ A, int lda, int Mv,
                       const float* __restrict__ B, int bn,
                       float* __restrict__ C, int ldc)
{
    float (*As)[68] = (float(*)[68])(&g.As[0][0]);
    const int tid = threadIdx.x;
    const int ty = tid >> 4, tx = tid & 15;
    const int am = tid >> 2, ak = (tid & 3) << 2;
    const int wk = tid >> 4, wc = (tid & 15) << 3;
    const int ams = (am < Mv) ? am : (Mv - 1);

    float acc[4][8] = {};
    const float* aptr = A + (size_t)ams * lda + ak;
    const float* bptr = B + wk * 256 + bn + wc;
    float4 av = *(const float4*)aptr;
    float4 b0 = *(const float4*)bptr;
    float4 b1 = *(const float4*)(bptr + 4);

    for (int k0 = 0; k0 < 256; k0 += 16) {
        __syncthreads();
        As[ak + 0][am] = av.x; As[ak + 1][am] = av.y;
        As[ak + 2][am] = av.z; As[ak + 3][am] = av.w;
        *(float4*)&g.Ws[wk][wc]     = b0;
        *(float4*)&g.Ws[wk][wc + 4] = b1;
        __syncthreads();
        if (k0 + 16 < 256) {
            av = *(const float4*)(aptr + k0 + 16);
            b0 = *(const float4*)(bptr + (k0 + 16) * 256);
            b1 = *(const float4*)(bptr + (k0 + 16) * 256 + 4);
        }
#pragma unroll
        for (int kk = 0; kk < 16; ++kk) {
            const float4 a4 = *(const float4*)&As[kk][ty << 2];
            const float4 w0 = *(const float4*)&g.Ws[kk][tx << 2];
            const float4 w1 = *(const float4*)&g.Ws[kk][64 + (tx << 2)];
            const float a_[4] = {a4.x, a4.y, a4.z, a4.w};
            const float w_[8] = {w0.x, w0.y, w0.z, w0.w, w1.x, w1.y, w1.z, w1.w};
#pragma unroll
            for (int i = 0; i < 4; ++i)
#pragma unroll
                for (int jj = 0; jj < 8; ++jj)
                    acc[i][jj] = fmaf(a_[i], w_[jj], acc[i][jj]);
        }
    }

#pragma unroll
    for (int i = 0; i < 4; ++i) {
        const int rr = (ty << 2) + i;
        if (rr < Mv) {
            *(float4*)(C + (size_t)rr * ldc + (tx << 2)) =
                make_float4(acc[i][0], acc[i][1], acc[i][2], acc[i][3]);
            *(float4*)(C + (size_t)rr * ldc + 64 + (tx << 2)) =
                make_float4(acc[i][4], acc[i][5], acc[i][6], acc[i][7]);
        }
    }
}

// ---------------------------------------------------------------------------
// 128x128 tile gemm, 8x8 microtile: 4 x ds_read_b128 per 64 fma.
__device__ void gemm128(GemmS& g, const float* __restrict__ A,
                        const float* __restrict__ B, int bn,
                        float* __restrict__ C, int ldc)
{
    const int tid = threadIdx.x;
    const int ty = tid >> 4, tx = tid & 15;
    const int am = tid >> 1, ak = (tid & 1) << 3;
    const int wk = tid >> 4, wc = (tid & 15) << 3;

    float acc[8][8] = {};
    const float* aptr = A + (size_t)am * 256 + ak;
    const float* bptr = B + wk * 256 + bn + wc;
    float4 a0 = *(const float4*)aptr;
    float4 a1 = *(const float4*)(aptr + 4);
    float4 b0 = *(const float4*)bptr;
    float4 b1 = *(const float4*)(bptr + 4);

    for (int k0 = 0; k0 < 256; k0 += 16) {
        __syncthreads();
        g.As[ak + 0][am] = a0.x; g.As[ak + 1][am] = a0.y;
        g.As[ak + 2][am] = a0.z; g.As[ak + 3][am] = a0.w;
        g.As[ak + 4][am] = a1.x; g.As[ak + 5][am] = a1.y;
        g.As[ak + 6][am] = a1.z; g.As[ak + 7][am] = a1.w;
        *(float4*)&g.Ws[wk][wc]     = b0;
        *(float4*)&g.Ws[wk][wc + 4] = b1;
        __syncthreads();
        if (k0 + 16 < 256) {
            a0 = *(const float4*)(aptr + k0 + 16);
            a1 = *(const float4*)(aptr + k0 + 20);
            b0 = *(const float4*)(bptr + (k0 + 16) * 256);
            b1 = *(const float4*)(bptr + (k0 + 16) * 256 + 4);
        }
#pragma unroll
        for (int kk = 0; kk < 16; ++kk) {
            const float4 x0 = *(const float4*)&g.As[kk][ty << 3];
            const float4 x1 = *(const float4*)&g.As[kk][(ty << 3) + 4];
            const float4 y0 = *(const float4*)&g.Ws[kk][tx << 3];
            const float4 y1 = *(const float4*)&g.Ws[kk][(tx << 3) + 4];
            const float xa[8] = {x0.x, x0.y, x0.z, x0.w, x1.x, x1.y, x1.z, x1.w};
            const float yb[8] = {y0.x, y0.y, y0.z, y0.w, y1.x, y1.y, y1.z, y1.w};
#pragma unroll
            for (int i = 0; i < 8; ++i)
#pragma unroll
                for (int jj = 0; jj < 8; ++jj)
                    acc[i][jj] = fmaf(xa[i], yb[jj], acc[i][jj]);
        }
    }

#pragma unroll
    for (int i = 0; i < 8; ++i) {
        float* cr = C + (size_t)((ty << 3) + i) * ldc + (tx << 3);
        *(float4*)cr       = make_float4(acc[i][0], acc[i][1], acc[i][2], acc[i][3]);
        *(float4*)(cr + 4) = make_float4(acc[i][4], acc[i][5], acc[i][6], acc[i][7]);
    }
}

// ---------------------------------------------------------------------------
// Narrow router region: C(64 x 4 slice) = A(64 rows x 256) @ Wr(256 x 4).
__device__ void router_region(RtrS& rs, const float* __restrict__ A,
                              const float* __restrict__ Wr,
                              float* __restrict__ C, int ldc, int row0)
{
    const int tid = threadIdx.x;
    for (int idx = tid; idx < 1024; idx += 256)
        rs.WrT[idx & 3][idx >> 2] = Wr[idx];
    __syncthreads();
    const int row = row0 + (tid >> 2), c = tid & 3;
    const float* a = A + (size_t)row * 256;
    float acc = 0.f;
#pragma unroll 8
    for (int k4 = 0; k4 < 64; ++k4) {
        const float4 avv = *(const float4*)(a + (k4 << 2));
        const float4 wvv = *(const float4*)&rs.WrT[c][k4 << 2];
        acc = fmaf(avv.x, wvv.x, acc);
        acc = fmaf(avv.y, wvv.y, acc);
        acc = fmaf(avv.z, wvv.z, acc);
        acc = fmaf(avv.w, wvv.w, acc);
    }
    C[(size_t)row * ldc + c] = acc;
}

// ---------------------------------------------------------------------------
// Wg = W_gk1 @ W_gk2, 16 rows per job.
__device__ void wg_region(const float* __restrict__ Wg1,
                          const float* __restrict__ Wg2,
                          float* __restrict__ Wg, int k0)
{
    const int c = threadIdx.x;
    float w2[16];
#pragma unroll
    for (int i = 0; i < 16; ++i) w2[i] = Wg2[i * 256 + c];
#pragma unroll
    for (int r = 0; r < 16; ++r) {
        const int k = k0 + r;
        float s = 0.f;
#pragma unroll
        for (int i = 0; i < 16; ++i) s = fmaf(Wg1[k * 16 + i], w2[i], s);
        Wg[k * 256 + c] = s;
    }
}

// ---------------------------------------------------------------------------
// Single fused kernel, plain launch + software grid barrier.
// phase1: Wg, cond, qlast, KVb-router.  phase2: KVb k|v|p, Cb q|k|v|p|r.
// phase3: router + recurrence + RMSNorm + output projection (round-0 body).
__global__ __launch_bounds__(256, 2) void fused_all(
    const float* __restrict__ query, const float* __restrict__ keyval,
    const int* __restrict__ mask, const float* __restrict__ W_cond,
    const float* __restrict__ W_q, const float* __restrict__ W_k,
    const float* __restrict__ W_v, const float* __restrict__ W_gk1,
    const float* __restrict__ W_gk2, const float* __restrict__ b_gk2,
    const float* __restrict__ W_router, const float* __restrict__ norm_w,
    const float* __restrict__ W_o,
    float* __restrict__ Wg, float* __restrict__ KVb, float* __restrict__ cond,
    float* __restrict__ qlast, float* __restrict__ Cb,
    float* __restrict__ out, float* __restrict__ logits,
    unsigned* __restrict__ bar)
{
    __shared__ AllS S;
    const int bid = blockIdx.x;

    // ---------------- phase 1 (66 jobs on stride-7 bids)
    if (bid % 7 == 0) {
        const int jj = bid / 7;
        if (jj < 16) {
            wg_region(W_gk1, W_gk2, Wg, jj * 16);
        } else if (jj < 32) {
            const int t = jj - 16;               // cond: 8 row-tiles x 2 col
            gemm64(S.g, query + (size_t)(t >> 1) * 64 * 256, 256, 64,
                   W_cond, (t & 1) * 128,
                   cond + (size_t)(t >> 1) * 64 * 256 + (t & 1) * 128, 256);
        } else if (jj < 34) {                    // qlast: 8 rows x 256
            gemm64(S.g, keyval + 255 * 256, Kk * Dd, 8, W_q, (jj - 32) * 128,
                   qlast + (jj - 32) * 128, 256);
        } else if (jj < 66) {                    // KVb router cols
            router_region(S.r, keyval, W_router, KVb + 768, SKV, (jj - 34) * 64);
        }
    }
    gridbar(&bar[0], GRID);

    // ---------------- phase 2 (128 gemm jobs on even bids<256 + 8 router jobs)
    if (bid < 256) {
        if ((bid & 1) == 0) {
            const int jj = bid >> 1;
            if (jj < 96) {                       // KVb k|v|p: 16 rt x 6 ct
                const int rt = jj / 6, ct = jj % 6;
                const float* Bsel = (ct < 2) ? W_k : (ct < 4) ? W_v : Wg;
                gemm128(S.g, keyval + (size_t)rt * 128 * 256, Bsel, (ct & 1) * 128,
                        KVb + (size_t)rt * 128 * SKV + (ct >> 1) * 256
                            + (ct & 1) * 128, SKV);
            } else {                             // Cb q|k|v|p: 4 rt x 8 ct
                const int t = jj - 96, rt = t >> 3, ct = t & 7;
                const float* Bsel = (ct < 2) ? W_q : (ct < 4) ? W_k
                                  : (ct < 6) ? W_v : Wg;
                gemm128(S.g, cond + (size_t)rt * 128 * 256, Bsel, (ct & 1) * 128,
                        Cb + (size_t)rt * 128 * SCB + (ct >> 1) * 256
                           + (ct & 1) * 128, SCB);
            }
        } else if (bid < 16) {                   // Cb router cols (needs cond)
            router_region(S.r, cond, W_router, Cb + 1024, SCB,
                          ((bid - 1) >> 1) * 64);
        }
    }
    gridbar(&bar[1], GRID);

    // ---------------- phase 3: mom (round-0 proven body; n = bid)
    const int n = bid;
    const int b = n >> 6;
    const int j = threadIdx.x;
    const int lane = j & 63;
    const int wv = j >> 6;

    const float qc = Cb[(size_t)n * SCB + j];
    const float kc = Cb[(size_t)n * SCB + 256 + j];
    const float vc = Cb[(size_t)n * SCB + 512 + j];
    const float pc = Cb[(size_t)n * SCB + 768 + j] + b_gk2[j];
    const float4 rc = *(const float4*)(Cb + (size_t)n * SCB + 1024);

    const int* pm = mask + b * Kk;

    // router top-2 for t = j; logits out; weights to LDS
    {
        const float4 kvr = *(const float4*)(KVb + (size_t)(b * Kk + j) * SKV + 768);
        float l[4] = {kvr.x + rc.x, kvr.y + rc.y, kvr.z + rc.z, kvr.w + rc.w};
        *(float4*)(logits + ((size_t)n * Kk + j) * 4) =
            make_float4(l[0], l[1], l[2], l[3]);

        int i1 = 0;
#pragma unroll
        for (int q = 1; q < 4; ++q) if (l[q] > l[i1]) i1 = q;
        int i2 = -1;
#pragma unroll
        for (int q = 0; q < 4; ++q) {
            if (q == i1) continue;
            if (i2 < 0 || l[q] > l[i2]) i2 = q;
        }
        const float mx = fmaxf(l[i1], l[i2]);
        const float e1 = __expf(l[i1] - mx);
        const float e2 = __expf(l[i2] - mx);
        const float inv = 1.f / (e1 + e2);
        float w[4] = {0.f, 0.f, 0.f, 0.f};
        w[i1] = e1 * inv;
        w[i2] = e2 * inv;
        S.m.wm[j] = make_float4(w[0], w[1], w[2], w[3]);
    }
    __syncthreads();

    // reverse-sweep recurrence in 16-t tiles
    const float ql  = qlast[b * 256 + j] + qc;
    const float qkc = ql * kc;
    const float* pkv = KVb + (size_t)b * Kk * SKV + j;

    float E0 = 1.f, E1 = 1.f, E2 = 1.f, E3 = 1.f, E4 = 1.f;
    float o = 0.f;
    const int tl = lane & 15, qg = lane >> 4;

    for (int t0 = Kk - 16; t0 >= 0; t0 -= 16) {
        float vreg[16];
#pragma unroll
        for (int i = 0; i < 16; ++i) {
            const int t = t0 + 15 - i;           // descending t
            const float* r = pkv + (size_t)t * SKV;
            const float kraw = r[0];
            const float vraw = r[256];
            const float praw = r[512];
            const float mf  = (float)pm[t];
            const float pre = praw + pc;
            // dg = sigmoid(pre)^(1/16) = exp(-log(1+e^-pre)/16), inf-safe
            const float ee  = __expf(-pre);
            float dg = __expf(-0.0625f * __logf(1.f + ee));
            dg = (mf != 0.f) ? dg : 1.f;
            const float4 w = S.m.wm[t];
            const float zf = E0 + w.x * E1 + w.y * E2 + w.z * E3 + w.w * E4;
            const float qlk = fmaf(ql, kraw, qkc);
            S.m.Pt[wv][i][lane] = qlk * zf * mf;
            vreg[i] = vraw + vc;
            E0 *= dg;
            E1 *= (w.x > 0.f) ? dg : 1.f;
            E2 *= (w.y > 0.f) ? dg : 1.f;
            E3 *= (w.z > 0.f) ? dg : 1.f;
            E4 *= (w.w > 0.f) ? dg : 1.f;
        }
        __builtin_amdgcn_wave_barrier();

        // wave-local transpose-reduce: s[i] = sum_c P[i][c]
        float s = 0.f;
#pragma unroll
        for (int rr4 = 0; rr4 < 4; ++rr4) {
            const float4 p4 = *(const float4*)&S.m.Pt[wv][tl][qg * 16 + rr4 * 4];
            s += (p4.x + p4.y) + (p4.z + p4.w);
        }
        s += __shfl_xor(s, 16, 64);
        s += __shfl_xor(s, 32, 64);
        S.m.sbuf[wv][tl] = s;                    // same-value multi-write, benign
        __builtin_amdgcn_wave_barrier();
#pragma unroll
        for (int rr4 = 0; rr4 < 4; ++rr4) {
            const float4 sv = *(const float4*)&S.m.sbuf[wv][rr4 * 4];
            o = fmaf(sv.x, vreg[rr4 * 4 + 0], o);
            o = fmaf(sv.y, vreg[rr4 * 4 + 1], o);
            o = fmaf(sv.z, vreg[rr4 * 4 + 2], o);
            o = fmaf(sv.w, vreg[rr4 * 4 + 3], o);
        }
    }

    // fused RMSNorm over DV (per head = per wave)
    const float ms = wred(o * o) * (1.0f / 64.0f);
    S.m.onorm[j] = o * rsqrtf(ms + EPSf) * norm_w[lane];
    __syncthreads();

    // fused output projection: out[n,j] = onorm . W_o[:,j]
    float acc = 0.f;
#pragma unroll 8
    for (int k = 0; k < 256; ++k)
        acc = fmaf(S.m.onorm[k], W_o[(size_t)k * 256 + j], acc);
    out[(size_t)n * 256 + j] = acc;
}

// ---------------------------------------------------------------------------
extern "C" void kernel_launch(void* const* d_in, const int* in_sizes, int n_in,
                              void* d_out, int out_size, void* d_ws, size_t ws_size,
                              hipStream_t stream)
{
    const float* query    = (const float*)d_in[0];   // (8,64,256)
    const float* keyval   = (const float*)d_in[1];   // (8,256,256)
    const int*   mask     = (const int*)  d_in[2];   // (8,256)
    const float* W_cond   = (const float*)d_in[3];   // (256,256)
    const float* W_q      = (const float*)d_in[4];   // (256,256)
    const float* W_k      = (const float*)d_in[5];   // (256,256)
    const float* W_v      = (const float*)d_in[6];   // (256,256)
    const float* W_gk1    = (const float*)d_in[7];   // (256,16)
    const float* W_gk2    = (const float*)d_in[8];   // (16,256)
    const float* b_gk2    = (const float*)d_in[9];   // (256,)
    const float* W_router = (const float*)d_in[10];  // (256,4)
    const float* norm_w   = (const float*)d_in[11];  // (64,)
    const float* W_o      = (const float*)d_in[12];  // (256,256)

    float* out    = (float*)d_out;        // (8,64,256)
    float* logits = out + Nn * Dd;        // (N*K, 4)

    // workspace layout (floats)
    float* p = (float*)d_ws;
    float* Wg    = p; p += 256 * 256;       // 65536
    float* KVb   = p; p += 2048 * SKV;      // 1589248
    float* cond  = p; p += Nn * 256;        // 131072
    float* qlast = p; p += 8 * 256;         // 2048
    float* Cb    = p; p += Nn * SCB;        // 528384
    unsigned* bar = (unsigned*)p;           // barrier counters (memset below)

    hipMemsetAsync(bar, 0, 256, stream);
    fused_all<<<dim3(GRID), dim3(256), 0, stream>>>(
        query, keyval, mask, W_cond, W_q, W_k, W_v, W_gk1, W_gk2, b_gk2,
        W_router, norm_w, W_o,
        Wg, KVb, cond, qlast, Cb, out, logits, bar);
}

// Round 4
// 244.396 us; speedup vs baseline: 1.8411x; 1.8411x over previous
//
#include <hip/hip_runtime.h>
#include <math.h>

// Problem constants
#define Hh   4
#define Bb   8
#define Qq   64
#define Kk   256
#define Dd   256
#define Nn   (Bb * Qq)          // 512
#define GNf  16.0f
#define EPSf 1e-5f

#define SKV  776                // KVb row stride: [k(256)|v(256)|p(256)|r(4)|pad]
#define SCB  1032               // Cb  row stride: [q(256)|k(256)|v(256)|p(256)|r(4)|pad]

// ---------------------------------------------------------------------------
struct GemmS { float As[16][136]; float Ws[16][136]; };   // 17408 B
struct RtrS  { float WrT[4][260]; };                      // 4160 B
union  WorkS { GemmS g; RtrS r; };

// ---------------------------------------------------------------------------
__device__ __forceinline__ float wred(float x) {
#pragma unroll
    for (int off = 32; off > 0; off >>= 1)
        x += __shfl_xor(x, off, 64);
    return x;
}

// ---------------------------------------------------------------------------
// 64x128 tile gemm (validated r3): As transposed pitch-68, Ws pitch-136,
// inner loop = 3 x ds_read_b128 + 32 fma. Global prefetch across k0.
__device__ void gemm64(GemmS& g, const float* __restrict__ A, int lda, int Mv,
                       const float* __restrict__ B, int bn,
                       float* __restrict__ C, int ldc)
{
    float (*As)[68] = (float(*)[68])(&g.As[0][0]);
    const int tid = threadIdx.x;
    const int ty = tid >> 4, tx = tid & 15;
    const int am = tid >> 2, ak = (tid & 3) << 2;
    const int wk = tid >> 4, wc = (tid & 15) << 3;
    const int ams = (am < Mv) ? am : (Mv - 1);

    float acc[4][8] = {};
    const float* aptr = A + (size_t)ams * lda + ak;
    const float* bptr = B + wk * 256 + bn + wc;
    float4 av = *(const float4*)aptr;
    float4 b0 = *(const float4*)bptr;
    float4 b1 = *(const float4*)(bptr + 4);

    for (int k0 = 0; k0 < 256; k0 += 16) {
        __syncthreads();
        As[ak + 0][am] = av.x; As[ak + 1][am] = av.y;
        As[ak + 2][am] = av.z; As[ak + 3][am] = av.w;
        *(float4*)&g.Ws[wk][wc]     = b0;
        *(float4*)&g.Ws[wk][wc + 4] = b1;
        __syncthreads();
        if (k0 + 16 < 256) {
            av = *(const float4*)(aptr + k0 + 16);
            b0 = *(const float4*)(bptr + (k0 + 16) * 256);
            b1 = *(const float4*)(bptr + (k0 + 16) * 256 + 4);
        }
#pragma unroll
        for (int kk = 0; kk < 16; ++kk) {
            const float4 a4 = *(const float4*)&As[kk][ty << 2];
            const float4 w0 = *(const float4*)&g.Ws[kk][tx << 2];
            const float4 w1 = *(const float4*)&g.Ws[kk][64 + (tx << 2)];
            const float a_[4] = {a4.x, a4.y, a4.z, a4.w};
            const float w_[8] = {w0.x, w0.y, w0.z, w0.w, w1.x, w1.y, w1.z, w1.w};
#pragma unroll
            for (int i = 0; i < 4; ++i)
#pragma unroll
                for (int jj = 0; jj < 8; ++jj)
                    acc[i][jj] = fmaf(a_[i], w_[jj], acc[i][jj]);
        }
    }

#pragma unroll
    for (int i = 0; i < 4; ++i) {
        const int rr = (ty << 2) + i;
        if (rr < Mv) {
            *(float4*)(C + (size_t)rr * ldc + (tx << 2)) =
                make_float4(acc[i][0], acc[i][1], acc[i][2], acc[i][3]);
            *(float4*)(C + (size_t)rr * ldc + 64 + (tx << 2)) =
                make_float4(acc[i][4], acc[i][5], acc[i][6], acc[i][7]);
        }
    }
}

// ---------------------------------------------------------------------------
// 128x128 tile gemm (validated r3), 8x8 microtile: 4 x ds_read_b128 / 64 fma.
__device__ void gemm128(GemmS& g, const float* __restrict__ A,
                        const float* __restrict__ B, int bn,
                        float* __restrict__ C, int ldc)
{
    const int tid = threadIdx.x;
    const int ty = tid >> 4, tx = tid & 15;
    const int am = tid >> 1, ak = (tid & 1) << 3;
    const int wk = tid >> 4, wc = (tid & 15) << 3;

    float acc[8][8] = {};
    const float* aptr = A + (size_t)am * 256 + ak;
    const float* bptr = B + wk * 256 + bn + wc;
    float4 a0 = *(const float4*)aptr;
    float4 a1 = *(const float4*)(aptr + 4);
    float4 b0 = *(const float4*)bptr;
    float4 b1 = *(const float4*)(bptr + 4);

    for (int k0 = 0; k0 < 256; k0 += 16) {
        __syncthreads();
        g.As[ak + 0][am] = a0.x; g.As[ak + 1][am] = a0.y;
        g.As[ak + 2][am] = a0.z; g.As[ak + 3][am] = a0.w;
        g.As[ak + 4][am] = a1.x; g.As[ak + 5][am] = a1.y;
        g.As[ak + 6][am] = a1.z; g.As[ak + 7][am] = a1.w;
        *(float4*)&g.Ws[wk][wc]     = b0;
        *(float4*)&g.Ws[wk][wc + 4] = b1;
        __syncthreads();
        if (k0 + 16 < 256) {
            a0 = *(const float4*)(aptr + k0 + 16);
            a1 = *(const float4*)(aptr + k0 + 20);
            b0 = *(const float4*)(bptr + (k0 + 16) * 256);
            b1 = *(const float4*)(bptr + (k0 + 16) * 256 + 4);
        }
#pragma unroll
        for (int kk = 0; kk < 16; ++kk) {
            const float4 x0 = *(const float4*)&g.As[kk][ty << 3];
            const float4 x1 = *(const float4*)&g.As[kk][(ty << 3) + 4];
            const float4 y0 = *(const float4*)&g.Ws[kk][tx << 3];
            const float4 y1 = *(const float4*)&g.Ws[kk][(tx << 3) + 4];
            const float xa[8] = {x0.x, x0.y, x0.z, x0.w, x1.x, x1.y, x1.z, x1.w};
            const float yb[8] = {y0.x, y0.y, y0.z, y0.w, y1.x, y1.y, y1.z, y1.w};
#pragma unroll
            for (int i = 0; i < 8; ++i)
#pragma unroll
                for (int jj = 0; jj < 8; ++jj)
                    acc[i][jj] = fmaf(xa[i], yb[jj], acc[i][jj]);
        }
    }

#pragma unroll
    for (int i = 0; i < 8; ++i) {
        float* cr = C + (size_t)((ty << 3) + i) * ldc + (tx << 3);
        *(float4*)cr       = make_float4(acc[i][0], acc[i][1], acc[i][2], acc[i][3]);
        *(float4*)(cr + 4) = make_float4(acc[i][4], acc[i][5], acc[i][6], acc[i][7]);
    }
}

// ---------------------------------------------------------------------------
// Narrow router region (validated r3): C(64x4) = A(64x256) @ Wr(256x4).
__device__ void router_region(RtrS& rs, const float* __restrict__ A,
                              const float* __restrict__ Wr,
                              float* __restrict__ C, int ldc, int row0)
{
    const int tid = threadIdx.x;
    for (int idx = tid; idx < 1024; idx += 256)
        rs.WrT[idx & 3][idx >> 2] = Wr[idx];
    __syncthreads();
    const int row = row0 + (tid >> 2), c = tid & 3;
    const float* a = A + (size_t)row * 256;
    float acc = 0.f;
#pragma unroll 8
    for (int k4 = 0; k4 < 64; ++k4) {
        const float4 avv = *(const float4*)(a + (k4 << 2));
        const float4 wvv = *(const float4*)&rs.WrT[c][k4 << 2];
        acc = fmaf(avv.x, wvv.x, acc);
        acc = fmaf(avv.y, wvv.y, acc);
        acc = fmaf(avv.z, wvv.z, acc);
        acc = fmaf(avv.w, wvv.w, acc);
    }
    C[(size_t)row * ldc + c] = acc;
}

// ---------------------------------------------------------------------------
// Wg = W_gk1 @ W_gk2, 16 rows per job (validated r3).
__device__ void wg_region(const float* __restrict__ Wg1,
                          const float* __restrict__ Wg2,
                          float* __restrict__ Wg, int k0)
{
    const int c = threadIdx.x;
    float w2[16];
#pragma unroll
    for (int i = 0; i < 16; ++i) w2[i] = Wg2[i * 256 + c];
#pragma unroll
    for (int r = 0; r < 16; ++r) {
        const int k = k0 + r;
        float s = 0.f;
#pragma unroll
        for (int i = 0; i < 16; ++i) s = fmaf(Wg1[k * 16 + i], w2[i], s);
        Wg[k * 256 + c] = s;
    }
}

// ---------------------------------------------------------------------------
// K1: Wg + cond + qlast + KVb router cols (66 blocks)
__global__ __launch_bounds__(256, 2) void k1(
    const float* __restrict__ query, const float* __restrict__ keyval,
    const float* __restrict__ W_cond, const float* __restrict__ W_q,
    const float* __restrict__ W_gk1, const float* __restrict__ W_gk2,
    const float* __restrict__ W_router,
    float* __restrict__ Wg, float* __restrict__ cond,
    float* __restrict__ qlast, float* __restrict__ KVb)
{
    __shared__ WorkS S;
    const int id = blockIdx.x;
    if (id < 16) {
        wg_region(W_gk1, W_gk2, Wg, id * 16);
    } else if (id < 32) {
        const int t = id - 16;                   // cond: 8 row-tiles x 2 col
        gemm64(S.g, query + (size_t)(t >> 1) * 64 * 256, 256, 64,
               W_cond, (t & 1) * 128,
               cond + (size_t)(t >> 1) * 64 * 256 + (t & 1) * 128, 256);
    } else if (id < 34) {                        // qlast: 8 rows x 256
        gemm64(S.g, keyval + 255 * 256, Kk * Dd, 8, W_q, (id - 32) * 128,
               qlast + (id - 32) * 128, 256);
    } else {                                     // KVb router cols
        router_region(S.r, keyval, W_router, KVb + 768, SKV, (id - 34) * 64);
    }
}

// ---------------------------------------------------------------------------
// K2: KVb k|v|p + Cb q|k|v|p + Cb router cols (136 blocks)
__global__ __launch_bounds__(256, 2) void k2(
    const float* __restrict__ keyval, const float* __restrict__ cond,
    const float* __restrict__ W_q, const float* __restrict__ W_k,
    const float* __restrict__ W_v, const float* __restrict__ Wg,
    const float* __restrict__ W_router,
    float* __restrict__ KVb, float* __restrict__ Cb)
{
    __shared__ WorkS S;
    const int id = blockIdx.x;
    if (id < 96) {                               // KVb k|v|p: 16 rt x 6 ct
        const int rt = id / 6, ct = id % 6;
        const float* Bsel = (ct < 2) ? W_k : (ct < 4) ? W_v : Wg;
        gemm128(S.g, keyval + (size_t)rt * 128 * 256, Bsel, (ct & 1) * 128,
                KVb + (size_t)rt * 128 * SKV + (ct >> 1) * 256 + (ct & 1) * 128,
                SKV);
    } else if (id < 128) {                       // Cb q|k|v|p: 4 rt x 8 ct
        const int t = id - 96, rt = t >> 3, ct = t & 7;
        const float* Bsel = (ct < 2) ? W_q : (ct < 4) ? W_k
                          : (ct < 6) ? W_v : Wg;
        gemm128(S.g, cond + (size_t)rt * 128 * 256, Bsel, (ct & 1) * 128,
                Cb + (size_t)rt * 128 * SCB + (ct >> 1) * 256 + (ct & 1) * 128,
                SCB);
    } else {                                     // Cb router cols
        router_region(S.r, cond, W_router, Cb + 1024, SCB, (id - 128) * 64);
    }
}

// ---------------------------------------------------------------------------
// K3: mom — exact round-3-validated phase-3 body (round-0 structure +
// inf-safe dg + qkc fold). One block per n.
__global__ __launch_bounds__(256) void mom_fused(
    const float* __restrict__ KVb, const float* __restrict__ Cb,
    const float* __restrict__ qlast, const float* __restrict__ b_gk2,
    const int* __restrict__ mask, const float* __restrict__ W_o,
    const float* __restrict__ norm_w, float* __restrict__ out,
    float* __restrict__ logits)
{
    __shared__ float4 wm[Kk];
    __shared__ float  Pt[4][16][68];
    __shared__ float  sbuf[4][16];
    __shared__ float  onorm[Dd];

    const int n = blockIdx.x;
    const int b = n >> 6;
    const int j = threadIdx.x;
    const int lane = j & 63;
    const int wv = j >> 6;

    const float qc = Cb[(size_t)n * SCB + j];
    const float kc = Cb[(size_t)n * SCB + 256 + j];
    const float vc = Cb[(size_t)n * SCB + 512 + j];
    const float pc = Cb[(size_t)n * SCB + 768 + j] + b_gk2[j];
    const float4 rc = *(const float4*)(Cb + (size_t)n * SCB + 1024);

    const int* pm = mask + b * Kk;

    // router top-2 for t = j; logits out; weights to LDS
    {
        const float4 kvr = *(const float4*)(KVb + (size_t)(b * Kk + j) * SKV + 768);
        float l[4] = {kvr.x + rc.x, kvr.y + rc.y, kvr.z + rc.z, kvr.w + rc.w};
        *(float4*)(logits + ((size_t)n * Kk + j) * 4) =
            make_float4(l[0], l[1], l[2], l[3]);

        int i1 = 0;
#pragma unroll
        for (int q = 1; q < 4; ++q) if (l[q] > l[i1]) i1 = q;
        int i2 = -1;
#pragma unroll
        for (int q = 0; q < 4; ++q) {
            if (q == i1) continue;
            if (i2 < 0 || l[q] > l[i2]) i2 = q;
        }
        const float mx = fmaxf(l[i1], l[i2]);
        const float e1 = __expf(l[i1] - mx);
        const float e2 = __expf(l[i2] - mx);
        const float inv = 1.f / (e1 + e2);
        float w[4] = {0.f, 0.f, 0.f, 0.f};
        w[i1] = e1 * inv;
        w[i2] = e2 * inv;
        wm[j] = make_float4(w[0], w[1], w[2], w[3]);
    }
    __syncthreads();

    // reverse-sweep recurrence in 16-t tiles
    const float ql  = qlast[b * 256 + j] + qc;
    const float qkc = ql * kc;
    const float* pkv = KVb + (size_t)b * Kk * SKV + j;

    float E0 = 1.f, E1 = 1.f, E2 = 1.f, E3 = 1.f, E4 = 1.f;
    float o = 0.f;
    const int tl = lane & 15, qg = lane >> 4;

    for (int t0 = Kk - 16; t0 >= 0; t0 -= 16) {
        float vreg[16];
#pragma unroll
        for (int i = 0; i < 16; ++i) {
            const int t = t0 + 15 - i;           // descending t
            const float* r = pkv + (size_t)t * SKV;
            const float kraw = r[0];
            const float vraw = r[256];
            const float praw = r[512];
            const float mf  = (float)pm[t];
            const float pre = praw + pc;
            // dg = sigmoid(pre)^(1/16) = exp(-log(1+e^-pre)/16), inf-safe
            const float ee  = __expf(-pre);
            float dg = __expf(-0.0625f * __logf(1.f + ee));
            dg = (mf != 0.f) ? dg : 1.f;
            const float4 w = wm[t];
            const float zf = E0 + w.x * E1 + w.y * E2 + w.z * E3 + w.w * E4;
            const float qlk = fmaf(ql, kraw, qkc);
            Pt[wv][i][lane] = qlk * zf * mf;
            vreg[i] = vraw + vc;
            E0 *= dg;
            E1 *= (w.x > 0.f) ? dg : 1.f;
            E2 *= (w.y > 0.f) ? dg : 1.f;
            E3 *= (w.z > 0.f) ? dg : 1.f;
            E4 *= (w.w > 0.f) ? dg : 1.f;
        }
        __builtin_amdgcn_wave_barrier();

        // wave-local transpose-reduce: s[i] = sum_c P[i][c]
        float s = 0.f;
#pragma unroll
        for (int rr4 = 0; rr4 < 4; ++rr4) {
            const float4 p4 = *(const float4*)&Pt[wv][tl][qg * 16 + rr4 * 4];
            s += (p4.x + p4.y) + (p4.z + p4.w);
        }
        s += __shfl_xor(s, 16, 64);
        s += __shfl_xor(s, 32, 64);
        sbuf[wv][tl] = s;                        // same-value multi-write, benign
        __builtin_amdgcn_wave_barrier();
#pragma unroll
        for (int rr4 = 0; rr4 < 4; ++rr4) {
            const float4 sv = *(const float4*)&sbuf[wv][rr4 * 4];
            o = fmaf(sv.x, vreg[rr4 * 4 + 0], o);
            o = fmaf(sv.y, vreg[rr4 * 4 + 1], o);
            o = fmaf(sv.z, vreg[rr4 * 4 + 2], o);
            o = fmaf(sv.w, vreg[rr4 * 4 + 3], o);
        }
    }

    // fused RMSNorm over DV (per head = per wave)
    const float ms = wred(o * o) * (1.0f / 64.0f);
    onorm[j] = o * rsqrtf(ms + EPSf) * norm_w[lane];
    __syncthreads();

    // fused output projection: out[n,j] = onorm . W_o[:,j]
    float acc = 0.f;
#pragma unroll 8
    for (int k = 0; k < 256; ++k)
        acc = fmaf(onorm[k], W_o[(size_t)k * 256 + j], acc);
    out[(size_t)n * 256 + j] = acc;
}

// ---------------------------------------------------------------------------
extern "C" void kernel_launch(void* const* d_in, const int* in_sizes, int n_in,
                              void* d_out, int out_size, void* d_ws, size_t ws_size,
                              hipStream_t stream)
{
    const float* query    = (const float*)d_in[0];   // (8,64,256)
    const float* keyval   = (const float*)d_in[1];   // (8,256,256)
    const int*   mask     = (const int*)  d_in[2];   // (8,256)
    const float* W_cond   = (const float*)d_in[3];   // (256,256)
    const float* W_q      = (const float*)d_in[4];   // (256,256)
    const float* W_k      = (const float*)d_in[5];   // (256,256)
    const float* W_v      = (const float*)d_in[6];   // (256,256)
    const float* W_gk1    = (const float*)d_in[7];   // (256,16)
    const float* W_gk2    = (const float*)d_in[8];   // (16,256)
    const float* b_gk2    = (const float*)d_in[9];   // (256,)
    const float* W_router = (const float*)d_in[10];  // (256,4)
    const float* norm_w   = (const float*)d_in[11];  // (64,)
    const float* W_o      = (const float*)d_in[12];  // (256,256)

    float* out    = (float*)d_out;        // (8,64,256)
    float* logits = out + Nn * Dd;        // (N*K, 4)

    // workspace layout (floats)
    float* p = (float*)d_ws;
    float* Wg    = p; p += 256 * 256;
    float* KVb   = p; p += 2048 * SKV;
    float* cond  = p; p += Nn * 256;
    float* qlast = p; p += 8 * 256;
    float* Cb    = p; p += Nn * SCB;

    k1<<<66, dim3(256), 0, stream>>>(
        query, keyval, W_cond, W_q, W_gk1, W_gk2, W_router,
        Wg, cond, qlast, KVb);

    k2<<<136, dim3(256), 0, stream>>>(
        keyval, cond, W_q, W_k, W_v, Wg, W_router, KVb, Cb);

    mom_fused<<<Nn, dim3(256), 0, stream>>>(
        KVb, Cb, qlast, b_gk2, mask, W_o, norm_w, out, logits);
}

// Round 5
// 240.503 us; speedup vs baseline: 1.8709x; 1.0162x over previous
//
#include <hip/hip_runtime.h>
#include <math.h>

// Problem constants
#define Hh   4
#define Bb   8
#define Qq   64
#define Kk   256
#define Dd   256
#define Nn   (Bb * Qq)          // 512
#define GNf  16.0f
#define EPSf 1e-5f

#define SKV  776                // KVb row stride: [k(256)|v(256)|p(256)|r(4)|pad]
#define SCB  1032               // Cb  row stride: [q(256)|k(256)|v(256)|p(256)|r(4)|pad]

// ---------------------------------------------------------------------------
struct GemmS { float As[16][136]; float Ws[16][136]; };   // 17408 B
struct RtrS  { float WrT[4][260]; };                      // 4160 B
union  WorkS { GemmS g; RtrS r; };

// ---------------------------------------------------------------------------
__device__ __forceinline__ float wred(float x) {
#pragma unroll
    for (int off = 32; off > 0; off >>= 1)
        x += __shfl_xor(x, off, 64);
    return x;
}

// ---------------------------------------------------------------------------
// 64x128 tile gemm (validated r1/r3/r4): As transposed pitch-68, Ws pitch-136,
// inner loop = 3 x ds_read_b128 + 32 fma. Global prefetch across k0.
__device__ void gemm64(GemmS& g, const float* __restrict__ A, int lda, int Mv,
                       const float* __restrict__ B, int bn,
                       float* __restrict__ C, int ldc)
{
    float (*As)[68] = (float(*)[68])(&g.As[0][0]);
    const int tid = threadIdx.x;
    const int ty = tid >> 4, tx = tid & 15;
    const int am = tid >> 2, ak = (tid & 3) << 2;
    const int wk = tid >> 4, wc = (tid & 15) << 3;
    const int ams = (am < Mv) ? am : (Mv - 1);

    float acc[4][8] = {};
    const float* aptr = A + (size_t)ams * lda + ak;
    const float* bptr = B + wk * 256 + bn + wc;
    float4 av = *(const float4*)aptr;
    float4 b0 = *(const float4*)bptr;
    float4 b1 = *(const float4*)(bptr + 4);

    for (int k0 = 0; k0 < 256; k0 += 16) {
        __syncthreads();
        As[ak + 0][am] = av.x; As[ak + 1][am] = av.y;
        As[ak + 2][am] = av.z; As[ak + 3][am] = av.w;
        *(float4*)&g.Ws[wk][wc]     = b0;
        *(float4*)&g.Ws[wk][wc + 4] = b1;
        __syncthreads();
        if (k0 + 16 < 256) {
            av = *(const float4*)(aptr + k0 + 16);
            b0 = *(const float4*)(bptr + (k0 + 16) * 256);
            b1 = *(const float4*)(bptr + (k0 + 16) * 256 + 4);
        }
#pragma unroll
        for (int kk = 0; kk < 16; ++kk) {
            const float4 a4 = *(const float4*)&As[kk][ty << 2];
            const float4 w0 = *(const float4*)&g.Ws[kk][tx << 2];
            const float4 w1 = *(const float4*)&g.Ws[kk][64 + (tx << 2)];
            const float a_[4] = {a4.x, a4.y, a4.z, a4.w};
            const float w_[8] = {w0.x, w0.y, w0.z, w0.w, w1.x, w1.y, w1.z, w1.w};
#pragma unroll
            for (int i = 0; i < 4; ++i)
#pragma unroll
                for (int jj = 0; jj < 8; ++jj)
                    acc[i][jj] = fmaf(a_[i], w_[jj], acc[i][jj]);
        }
    }

#pragma unroll
    for (int i = 0; i < 4; ++i) {
        const int rr = (ty << 2) + i;
        if (rr < Mv) {
            *(float4*)(C + (size_t)rr * ldc + (tx << 2)) =
                make_float4(acc[i][0], acc[i][1], acc[i][2], acc[i][3]);
            *(float4*)(C + (size_t)rr * ldc + 64 + (tx << 2)) =
                make_float4(acc[i][4], acc[i][5], acc[i][6], acc[i][7]);
        }
    }
}

// ---------------------------------------------------------------------------
// Narrow router region (validated): C(64x4) = A(64x256) @ Wr(256x4).
__device__ void router_region(RtrS& rs, const float* __restrict__ A,
                              const float* __restrict__ Wr,
                              float* __restrict__ C, int ldc, int row0)
{
    const int tid = threadIdx.x;
    for (int idx = tid; idx < 1024; idx += 256)
        rs.WrT[idx & 3][idx >> 2] = Wr[idx];
    __syncthreads();
    const int row = row0 + (tid >> 2), c = tid & 3;
    const float* a = A + (size_t)row * 256;
    float acc = 0.f;
#pragma unroll 8
    for (int k4 = 0; k4 < 64; ++k4) {
        const float4 avv = *(const float4*)(a + (k4 << 2));
        const float4 wvv = *(const float4*)&rs.WrT[c][k4 << 2];
        acc = fmaf(avv.x, wvv.x, acc);
        acc = fmaf(avv.y, wvv.y, acc);
        acc = fmaf(avv.z, wvv.z, acc);
        acc = fmaf(avv.w, wvv.w, acc);
    }
    C[(size_t)row * ldc + c] = acc;
}

// ---------------------------------------------------------------------------
// Wg = W_gk1 @ W_gk2, 16 rows per job (validated).
__device__ void wg_region(const float* __restrict__ Wg1,
                          const float* __restrict__ Wg2,
                          float* __restrict__ Wg, int k0)
{
    const int c = threadIdx.x;
    float w2[16];
#pragma unroll
    for (int i = 0; i < 16; ++i) w2[i] = Wg2[i * 256 + c];
#pragma unroll
    for (int r = 0; r < 16; ++r) {
        const int k = k0 + r;
        float s = 0.f;
#pragma unroll
        for (int i = 0; i < 16; ++i) s = fmaf(Wg1[k * 16 + i], w2[i], s);
        Wg[k * 256 + c] = s;
    }
}

// ---------------------------------------------------------------------------
// K1: Wg + cond + qlast + KVb router cols (66 blocks)
__global__ __launch_bounds__(256) void k1(
    const float* __restrict__ query, const float* __restrict__ keyval,
    const float* __restrict__ W_cond, const float* __restrict__ W_q,
    const float* __restrict__ W_gk1, const float* __restrict__ W_gk2,
    const float* __restrict__ W_router,
    float* __restrict__ Wg, float* __restrict__ cond,
    float* __restrict__ qlast, float* __restrict__ KVb)
{
    __shared__ WorkS S;
    const int id = blockIdx.x;
    if (id < 16) {
        wg_region(W_gk1, W_gk2, Wg, id * 16);
    } else if (id < 32) {
        const int t = id - 16;                   // cond: 8 row-tiles x 2 col
        gemm64(S.g, query + (size_t)(t >> 1) * 64 * 256, 256, 64,
               W_cond, (t & 1) * 128,
               cond + (size_t)(t >> 1) * 64 * 256 + (t & 1) * 128, 256);
    } else if (id < 34) {                        // qlast: 8 rows x 256
        gemm64(S.g, keyval + 255 * 256, Kk * Dd, 8, W_q, (id - 32) * 128,
               qlast + (id - 32) * 128, 256);
    } else {                                     // KVb router cols
        router_region(S.r, keyval, W_router, KVb + 768, SKV, (id - 34) * 64);
    }
}

// ---------------------------------------------------------------------------
// K2: KVb k|v|p (192 gemm64) + Cb q|k|v|p (64 gemm64) + Cb router (8).
// All 64x128 tiles: the r1-validated fast configuration. 264 blocks ~ 1/CU.
__global__ __launch_bounds__(256) void k2(
    const float* __restrict__ keyval, const float* __restrict__ cond,
    const float* __restrict__ W_q, const float* __restrict__ W_k,
    const float* __restrict__ W_v, const float* __restrict__ Wg,
    const float* __restrict__ W_router,
    float* __restrict__ KVb, float* __restrict__ Cb)
{
    __shared__ WorkS S;
    const int id = blockIdx.x;
    if (id < 192) {                              // KVb k|v|p: 32 rt x 6 ct
        const int rt = id / 6, ct = id % 6;
        const float* Bsel = (ct < 2) ? W_k : (ct < 4) ? W_v : Wg;
        gemm64(S.g, keyval + (size_t)rt * 64 * 256, 256, 64,
               Bsel, (ct & 1) * 128,
               KVb + (size_t)rt * 64 * SKV + (ct >> 1) * 256 + (ct & 1) * 128,
               SKV);
    } else if (id < 256) {                       // Cb q|k|v|p: 4 rg x 8 rt x 2 ct
        const int t = id - 192, rg = t >> 4, rt = (t & 15) >> 1, ct = t & 1;
        const float* Bsel = (rg == 0) ? W_q : (rg == 1) ? W_k
                          : (rg == 2) ? W_v : Wg;
        gemm64(S.g, cond + (size_t)rt * 64 * 256, 256, 64,
               Bsel, ct * 128,
               Cb + (size_t)rt * 64 * SCB + rg * 256 + ct * 128, SCB);
    } else {                                     // Cb router cols
        router_region(S.r, cond, W_router, Cb + 1024, SCB, (id - 256) * 64);
    }
}

// ---------------------------------------------------------------------------
// K3: mom — r4-validated body + batched register prefetch of the 16-t tile
// (48 global loads issued back-to-back, then pure-register compute loop).
__global__ __launch_bounds__(256) void mom_fused(
    const float* __restrict__ KVb, const float* __restrict__ Cb,
    const float* __restrict__ qlast, const float* __restrict__ b_gk2,
    const int* __restrict__ mask, const float* __restrict__ W_o,
    const float* __restrict__ norm_w, float* __restrict__ out,
    float* __restrict__ logits)
{
    __shared__ float4 wm[Kk];
    __shared__ float  Pt[4][16][68];
    __shared__ float  sbuf[4][16];
    __shared__ float  onorm[Dd];

    const int n = blockIdx.x;
    const int b = n >> 6;
    const int j = threadIdx.x;
    const int lane = j & 63;
    const int wv = j >> 6;

    const float qc = Cb[(size_t)n * SCB + j];
    const float kc = Cb[(size_t)n * SCB + 256 + j];
    const float vc = Cb[(size_t)n * SCB + 512 + j];
    const float pc = Cb[(size_t)n * SCB + 768 + j] + b_gk2[j];
    const float4 rc = *(const float4*)(Cb + (size_t)n * SCB + 1024);

    const int* pm = mask + b * Kk;

    // router top-2 for t = j; logits out; weights to LDS
    {
        const float4 kvr = *(const float4*)(KVb + (size_t)(b * Kk + j) * SKV + 768);
        float l[4] = {kvr.x + rc.x, kvr.y + rc.y, kvr.z + rc.z, kvr.w + rc.w};
        *(float4*)(logits + ((size_t)n * Kk + j) * 4) =
            make_float4(l[0], l[1], l[2], l[3]);

        int i1 = 0;
#pragma unroll
        for (int q = 1; q < 4; ++q) if (l[q] > l[i1]) i1 = q;
        int i2 = -1;
#pragma unroll
        for (int q = 0; q < 4; ++q) {
            if (q == i1) continue;
            if (i2 < 0 || l[q] > l[i2]) i2 = q;
        }
        const float mx = fmaxf(l[i1], l[i2]);
        const float e1 = __expf(l[i1] - mx);
        const float e2 = __expf(l[i2] - mx);
        const float inv = 1.f / (e1 + e2);
        float w[4] = {0.f, 0.f, 0.f, 0.f};
        w[i1] = e1 * inv;
        w[i2] = e2 * inv;
        wm[j] = make_float4(w[0], w[1], w[2], w[3]);
    }
    __syncthreads();

    // reverse-sweep recurrence in 16-t tiles
    const float ql  = qlast[b * 256 + j] + qc;
    const float qkc = ql * kc;
    const float* pkv = KVb + (size_t)b * Kk * SKV + j;

    float E0 = 1.f, E1 = 1.f, E2 = 1.f, E3 = 1.f, E4 = 1.f;
    float o = 0.f;
    const int tl = lane & 15, qg = lane >> 4;

    for (int t0 = Kk - 16; t0 >= 0; t0 -= 16) {
        // ---- batched tile prefetch: 48 independent loads, no consumer
        //      in between -> memory burst overlaps with issue/scheduling
        float ka[16], va[16], pa[16];
#pragma unroll
        for (int i = 0; i < 16; ++i) {
            const float* r = pkv + (size_t)(t0 + 15 - i) * SKV;
            ka[i] = r[0];
            va[i] = r[256];
            pa[i] = r[512];
        }
        // ---- pure-register compute loop
#pragma unroll
        for (int i = 0; i < 16; ++i) {
            const int t = t0 + 15 - i;           // descending t
            const float mf  = (float)pm[t];
            const float pre = pa[i] + pc;
            // dg = sigmoid(pre)^(1/16) = exp(-log(1+e^-pre)/16), inf-safe
            const float ee  = __expf(-pre);
            float dg = __expf(-0.0625f * __logf(1.f + ee));
            dg = (mf != 0.f) ? dg : 1.f;
            const float4 w = wm[t];
            const float zf = E0 + w.x * E1 + w.y * E2 + w.z * E3 + w.w * E4;
            const float qlk = fmaf(ql, ka[i], qkc);
            Pt[wv][i][lane] = qlk * zf * mf;
            va[i] = va[i] + vc;
            E0 *= dg;
            E1 *= (w.x > 0.f) ? dg : 1.f;
            E2 *= (w.y > 0.f) ? dg : 1.f;
            E3 *= (w.z > 0.f) ? dg : 1.f;
            E4 *= (w.w > 0.f) ? dg : 1.f;
        }
        __builtin_amdgcn_wave_barrier();

        // wave-local transpose-reduce: s[i] = sum_c P[i][c]
        float s = 0.f;
#pragma unroll
        for (int rr4 = 0; rr4 < 4; ++rr4) {
            const float4 p4 = *(const float4*)&Pt[wv][tl][qg * 16 + rr4 * 4];
            s += (p4.x + p4.y) + (p4.z + p4.w);
        }
        s += __shfl_xor(s, 16, 64);
        s += __shfl_xor(s, 32, 64);
        sbuf[wv][tl] = s;                        // same-value multi-write, benign
        __builtin_amdgcn_wave_barrier();
#pragma unroll
        for (int rr4 = 0; rr4 < 4; ++rr4) {
            const float4 sv = *(const float4*)&sbuf[wv][rr4 * 4];
            o = fmaf(sv.x, va[rr4 * 4 + 0], o);
            o = fmaf(sv.y, va[rr4 * 4 + 1], o);
            o = fmaf(sv.z, va[rr4 * 4 + 2], o);
            o = fmaf(sv.w, va[rr4 * 4 + 3], o);
        }
    }

    // fused RMSNorm over DV (per head = per wave)
    const float ms = wred(o * o) * (1.0f / 64.0f);
    onorm[j] = o * rsqrtf(ms + EPSf) * norm_w[lane];
    __syncthreads();

    // fused output projection: out[n,j] = onorm . W_o[:,j]
    float acc = 0.f;
#pragma unroll 8
    for (int k = 0; k < 256; ++k)
        acc = fmaf(onorm[k], W_o[(size_t)k * 256 + j], acc);
    out[(size_t)n * 256 + j] = acc;
}

// ---------------------------------------------------------------------------
extern "C" void kernel_launch(void* const* d_in, const int* in_sizes, int n_in,
                              void* d_out, int out_size, void* d_ws, size_t ws_size,
                              hipStream_t stream)
{
    const float* query    = (const float*)d_in[0];   // (8,64,256)
    const float* keyval   = (const float*)d_in[1];   // (8,256,256)
    const int*   mask     = (const int*)  d_in[2];   // (8,256)
    const float* W_cond   = (const float*)d_in[3];   // (256,256)
    const float* W_q      = (const float*)d_in[4];   // (256,256)
    const float* W_k      = (const float*)d_in[5];   // (256,256)
    const float* W_v      = (const float*)d_in[6];   // (256,256)
    const float* W_gk1    = (const float*)d_in[7];   // (256,16)
    const float* W_gk2    = (const float*)d_in[8];   // (16,256)
    const float* b_gk2    = (const float*)d_in[9];   // (256,)
    const float* W_router = (const float*)d_in[10];  // (256,4)
    const float* norm_w   = (const float*)d_in[11];  // (64,)
    const float* W_o      = (const float*)d_in[12];  // (256,256)

    float* out    = (float*)d_out;        // (8,64,256)
    float* logits = out + Nn * Dd;        // (N*K, 4)

    // workspace layout (floats)
    float* p = (float*)d_ws;
    float* Wg    = p; p += 256 * 256;
    float* KVb   = p; p += 2048 * SKV;
    float* cond  = p; p += Nn * 256;
    float* qlast = p; p += 8 * 256;
    float* Cb    = p; p += Nn * SCB;

    k1<<<66, dim3(256), 0, stream>>>(
        query, keyval, W_cond, W_q, W_gk1, W_gk2, W_router,
        Wg, cond, qlast, KVb);

    k2<<<264, dim3(256), 0, stream>>>(
        keyval, cond, W_q, W_k, W_v, Wg, W_router, KVb, Cb);

    mom_fused<<<Nn, dim3(256), 0, stream>>>(
        KVb, Cb, qlast, b_gk2, mask, W_o, norm_w, out, logits);
}

// Round 6
// 221.282 us; speedup vs baseline: 2.0334x; 1.0869x over previous
//
#include <hip/hip_runtime.h>
#include <math.h>

// Problem constants
#define Hh   4
#define Bb   8
#define Qq   64
#define Kk   256
#define Dd   256
#define Nn   (Bb * Qq)          // 512
#define GNf  16.0f
#define EPSf 1e-5f

// Row strides: MUST be multiples of 32 floats (128 B) so every per-t wave
// load stays 128B-aligned (2 L2 lines, not 3). R4/R5's 776/1032 violated
// this and cost mom ~13 us.
#define SKV  832                // KVb row: [k(256)|v(256)|p(256)|r(4)|pad]
#define SCB  1088               // Cb  row: [q(256)|k(256)|v(256)|p(256)|r(4)|pad]

// ---------------------------------------------------------------------------
struct GemmS { float As[16][136]; float Ws[16][136]; };   // 17408 B
struct RtrS  { float WrT[4][260]; };                      // 4160 B
union  WorkS { GemmS g; RtrS r; };

// ---------------------------------------------------------------------------
__device__ __forceinline__ float wred(float x) {
#pragma unroll
    for (int off = 32; off > 0; off >>= 1)
        x += __shfl_xor(x, off, 64);
    return x;
}

// ---------------------------------------------------------------------------
// prep: Wg = W_gk1 @ W_gk2 (256 x 256). One output element per thread.
__global__ __launch_bounds__(256) void prep(
    const float* __restrict__ Wg1, const float* __restrict__ Wg2,
    float* __restrict__ Wg)
{
    const int e = blockIdx.x * 256 + threadIdx.x;   // < 65536
    const int k = e >> 8, c = e & 255;
    float s = 0.f;
#pragma unroll
    for (int i = 0; i < 16; ++i)
        s = fmaf(Wg1[k * 16 + i], Wg2[i * 256 + c], s);
    Wg[e] = s;
}

// ---------------------------------------------------------------------------
// 64x128 tile gemm (validated R1/R3/R4/R5): As transposed pitch-68, Ws
// pitch-136, inner loop = 3 x ds_read_b128 + 32 fma. Prefetch across k0.
__device__ void gemm64(GemmS& g, const float* __restrict__ A, int lda, int Mv,
                       const float* __restrict__ B, int bn,
                       float* __restrict__ C, int ldc)
{
    float (*As)[68] = (float(*)[68])(&g.As[0][0]);
    const int tid = threadIdx.x;
    const int ty = tid >> 4, tx = tid & 15;
    const int am = tid >> 2, ak = (tid & 3) << 2;
    const int wk = tid >> 4, wc = (tid & 15) << 3;
    const int ams = (am < Mv) ? am : (Mv - 1);

    float acc[4][8] = {};
    const float* aptr = A + (size_t)ams * lda + ak;
    const float* bptr = B + wk * 256 + bn + wc;
    float4 av = *(const float4*)aptr;
    float4 b0 = *(const float4*)bptr;
    float4 b1 = *(const float4*)(bptr + 4);

    for (int k0 = 0; k0 < 256; k0 += 16) {
        __syncthreads();
        As[ak + 0][am] = av.x; As[ak + 1][am] = av.y;
        As[ak + 2][am] = av.z; As[ak + 3][am] = av.w;
        *(float4*)&g.Ws[wk][wc]     = b0;
        *(float4*)&g.Ws[wk][wc + 4] = b1;
        __syncthreads();
        if (k0 + 16 < 256) {
            av = *(const float4*)(aptr + k0 + 16);
            b0 = *(const float4*)(bptr + (k0 + 16) * 256);
            b1 = *(const float4*)(bptr + (k0 + 16) * 256 + 4);
        }
#pragma unroll
        for (int kk = 0; kk < 16; ++kk) {
            const float4 a4 = *(const float4*)&As[kk][ty << 2];
            const float4 w0 = *(const float4*)&g.Ws[kk][tx << 2];
            const float4 w1 = *(const float4*)&g.Ws[kk][64 + (tx << 2)];
            const float a_[4] = {a4.x, a4.y, a4.z, a4.w};
            const float w_[8] = {w0.x, w0.y, w0.z, w0.w, w1.x, w1.y, w1.z, w1.w};
#pragma unroll
            for (int i = 0; i < 4; ++i)
#pragma unroll
                for (int jj = 0; jj < 8; ++jj)
                    acc[i][jj] = fmaf(a_[i], w_[jj], acc[i][jj]);
        }
    }

#pragma unroll
    for (int i = 0; i < 4; ++i) {
        const int rr = (ty << 2) + i;
        if (rr < Mv) {
            *(float4*)(C + (size_t)rr * ldc + (tx << 2)) =
                make_float4(acc[i][0], acc[i][1], acc[i][2], acc[i][3]);
            *(float4*)(C + (size_t)rr * ldc + 64 + (tx << 2)) =
                make_float4(acc[i][4], acc[i][5], acc[i][6], acc[i][7]);
        }
    }
}

// ---------------------------------------------------------------------------
// Narrow router region (validated): C(64x4) = A(64x256) @ Wr(256x4).
__device__ void router_region(RtrS& rs, const float* __restrict__ A,
                              const float* __restrict__ Wr,
                              float* __restrict__ C, int ldc, int row0)
{
    const int tid = threadIdx.x;
    for (int idx = tid; idx < 1024; idx += 256)
        rs.WrT[idx & 3][idx >> 2] = Wr[idx];
    __syncthreads();
    const int row = row0 + (tid >> 2), c = tid & 3;
    const float* a = A + (size_t)row * 256;
    float acc = 0.f;
#pragma unroll 8
    for (int k4 = 0; k4 < 64; ++k4) {
        const float4 avv = *(const float4*)(a + (k4 << 2));
        const float4 wvv = *(const float4*)&rs.WrT[c][k4 << 2];
        acc = fmaf(avv.x, wvv.x, acc);
        acc = fmaf(avv.y, wvv.y, acc);
        acc = fmaf(avv.z, wvv.z, acc);
        acc = fmaf(avv.w, wvv.w, acc);
    }
    C[(size_t)row * ldc + c] = acc;
}

// ---------------------------------------------------------------------------
// gemm_main (R1-validated): KVb = keyval @ [W_k|W_v|Wg|W_router] (2048x832),
// cond = query @ W_cond, qlast = keyval[:,255,:] @ W_q.  242 blocks.
__global__ __launch_bounds__(256) void gemm_main(
    const float* __restrict__ keyval, const float* __restrict__ query,
    const float* __restrict__ W_k, const float* __restrict__ W_v,
    const float* __restrict__ Wg, const float* __restrict__ W_cond,
    const float* __restrict__ W_q, const float* __restrict__ W_router,
    float* __restrict__ KVb, float* __restrict__ cond,
    float* __restrict__ qlast)
{
    __shared__ WorkS S;
    const int id = blockIdx.x;
    if (id < 210) {
        const float* A; int lda, Mv; const float* Bm; int bn; float* C; int ldc;
        if (id < 192) {                       // keyval @ {W_k,W_v,Wg}
            const int rt = id / 6, ct = id % 6;
            const float* Bsel; int cbase;
            if (ct < 2)      { Bsel = W_k; cbase = 0; }
            else if (ct < 4) { Bsel = W_v; cbase = 256; }
            else             { Bsel = Wg;  cbase = 512; }
            A = keyval + (size_t)rt * 64 * 256; lda = 256; Mv = 64;
            Bm = Bsel; bn = (ct & 1) * 128;
            C = KVb + (size_t)rt * 64 * SKV + cbase + bn; ldc = SKV;
        } else if (id < 208) {                // query @ W_cond
            const int t = id - 192, rt = t >> 1, ct = t & 1;
            A = query + (size_t)rt * 64 * 256; lda = 256; Mv = 64;
            Bm = W_cond; bn = ct * 128;
            C = cond + (size_t)rt * 64 * 256 + ct * 128; ldc = 256;
        } else {                              // keyval last rows @ W_q (8 rows)
            const int ct = id - 208;
            A = keyval + 255 * 256; lda = Kk * Dd; Mv = 8;
            Bm = W_q; bn = ct * 128;
            C = qlast + ct * 128; ldc = 256;
        }
        gemm64(S.g, A, lda, Mv, Bm, bn, C, ldc);
    } else {                                  // KVb router cols (32 jobs)
        router_region(S.r, keyval, W_router, KVb + 768, SKV, (id - 210) * 64);
    }
}

// ---------------------------------------------------------------------------
// gemm_cb (R1-validated): Cb = cond @ [W_q|W_k|W_v|Wg|W_router] (512x1088).
__global__ __launch_bounds__(256) void gemm_cb(
    const float* __restrict__ cond,
    const float* __restrict__ W_q, const float* __restrict__ W_k,
    const float* __restrict__ W_v, const float* __restrict__ Wg,
    const float* __restrict__ W_router, float* __restrict__ Cb)
{
    __shared__ WorkS S;
    const int id = blockIdx.x;
    if (id < 64) {
        const int rg = id >> 4, t = id & 15, rt = t >> 1, ct = t & 1;
        const float* Bsel = (rg == 0) ? W_q : (rg == 1) ? W_k
                          : (rg == 2) ? W_v : Wg;
        gemm64(S.g, cond + (size_t)rt * 64 * 256, 256, 64,
               Bsel, ct * 128,
               Cb + (size_t)rt * 64 * SCB + rg * 256 + ct * 128, SCB);
    } else {
        router_region(S.r, cond, W_router, Cb + 1024, SCB, (id - 64) * 64);
    }
}

// ---------------------------------------------------------------------------
// mom: R0's proven 72.7us body (128B-aligned strides), with two micro-cuts:
//  - mask folded into decay exponent: dg = exp(ls * (mf/16))  (ls finite by
//    the fabs-guard, so mf=0 -> exp(0)=1; removes cmp+cndmask from the chain)
//  - ql*kc folded into one fma against precomputed qkc.
__global__ __launch_bounds__(256) void mom_fused(
    const float* __restrict__ KVb, const float* __restrict__ Cb,
    const float* __restrict__ qlast, const float* __restrict__ b_gk2,
    const int* __restrict__ mask, const float* __restrict__ W_o,
    const float* __restrict__ norm_w, float* __restrict__ out,
    float* __restrict__ logits)
{
    __shared__ float4 wm[Kk];
    __shared__ float  Pt[4][16][68];
    __shared__ float  sbuf[4][16];
    __shared__ float  onorm[Dd];

    const int n = blockIdx.x;
    const int b = n >> 6;
    const int j = threadIdx.x;
    const int lane = j & 63;
    const int wv = j >> 6;

    const float qc = Cb[(size_t)n * SCB + j];
    const float kc = Cb[(size_t)n * SCB + 256 + j];
    const float vc = Cb[(size_t)n * SCB + 512 + j];
    const float pc = Cb[(size_t)n * SCB + 768 + j] + b_gk2[j];
    const float4 rc = *(const float4*)(Cb + (size_t)n * SCB + 1024);

    const int* pm = mask + b * Kk;

    // router top-2 for t = j; logits out; weights to LDS
    {
        const float4 kvr = *(const float4*)(KVb + (size_t)(b * Kk + j) * SKV + 768);
        float l[4] = {kvr.x + rc.x, kvr.y + rc.y, kvr.z + rc.z, kvr.w + rc.w};
        *(float4*)(logits + ((size_t)n * Kk + j) * 4) =
            make_float4(l[0], l[1], l[2], l[3]);

        int i1 = 0;
#pragma unroll
        for (int q = 1; q < 4; ++q) if (l[q] > l[i1]) i1 = q;
        int i2 = -1;
#pragma unroll
        for (int q = 0; q < 4; ++q) {
            if (q == i1) continue;
            if (i2 < 0 || l[q] > l[i2]) i2 = q;
        }
        const float mx = fmaxf(l[i1], l[i2]);
        const float e1 = __expf(l[i1] - mx);
        const float e2 = __expf(l[i2] - mx);
        const float inv = 1.f / (e1 + e2);
        float w[4] = {0.f, 0.f, 0.f, 0.f};
        w[i1] = e1 * inv;
        w[i2] = e2 * inv;
        wm[j] = make_float4(w[0], w[1], w[2], w[3]);
    }
    __syncthreads();

    // reverse-sweep recurrence in 16-t tiles
    const float ql  = qlast[b * 256 + j] + qc;
    const float qkc = ql * kc;
    const float* pk = KVb + (size_t)b * Kk * SKV + j;
    const float* pv = pk + 256;
    const float* pp = pk + 512;

    float E0 = 1.f, E1 = 1.f, E2 = 1.f, E3 = 1.f, E4 = 1.f;
    float o = 0.f;
    const int tl = lane & 15, qg = lane >> 4;

    for (int t0 = Kk - 16; t0 >= 0; t0 -= 16) {
        float vreg[16];
        // phase A: per-t P into LDS tile, no cross-lane ops
#pragma unroll
        for (int i = 0; i < 16; ++i) {
            const int t = t0 + 15 - i;           // descending t
            const float mf   = (float)pm[t];     // wave-uniform
            const float kraw = pk[(size_t)t * SKV];
            const float vraw = pv[(size_t)t * SKV];
            const float praw = pp[(size_t)t * SKV];
            const float pre  = praw + pc;

            // log-sigmoid, numerically symmetric (R0 form); mf folded in
            const float ls = fminf(pre, 0.f)
                           - __logf(1.f + __expf(-fabsf(pre)));
            const float dg = __expf(ls * (0.0625f * mf));

            const float4 w  = wm[t];
            const float zf = E0 + w.x * E1 + w.y * E2 + w.z * E3 + w.w * E4;
            Pt[wv][i][lane] = fmaf(ql, kraw, qkc) * zf * mf;
            vreg[i] = vraw + vc;

            E0 *= dg;
            E1 *= (w.x > 0.f) ? dg : 1.f;
            E2 *= (w.y > 0.f) ? dg : 1.f;
            E3 *= (w.z > 0.f) ? dg : 1.f;
            E4 *= (w.w > 0.f) ? dg : 1.f;
        }
        __builtin_amdgcn_wave_barrier();

        // phase B (wave-local): s[i] = sum_c P[i][c]
        float s = 0.f;
#pragma unroll
        for (int rr4 = 0; rr4 < 4; ++rr4) {
            const float4 p4 = *(const float4*)&Pt[wv][tl][qg * 16 + rr4 * 4];
            s += (p4.x + p4.y) + (p4.z + p4.w);
        }
        s += __shfl_xor(s, 16, 64);
        s += __shfl_xor(s, 32, 64);
        sbuf[wv][tl] = s;                        // same-value multi-write, benign
        __builtin_amdgcn_wave_barrier();
#pragma unroll
        for (int rr4 = 0; rr4 < 4; ++rr4) {
            const float4 sv = *(const float4*)&sbuf[wv][rr4 * 4];
            o = fmaf(sv.x, vreg[rr4 * 4 + 0], o);
            o = fmaf(sv.y, vreg[rr4 * 4 + 1], o);
            o = fmaf(sv.z, vreg[rr4 * 4 + 2], o);
            o = fmaf(sv.w, vreg[rr4 * 4 + 3], o);
        }
    }

    // fused RMSNorm over DV (per head = per wave)
    const float ms = wred(o * o) * (1.0f / 64.0f);
    onorm[j] = o * rsqrtf(ms + EPSf) * norm_w[lane];
    __syncthreads();

    // fused output projection: out[n,j] = onorm . W_o[:,j]
    float acc = 0.f;
#pragma unroll 8
    for (int k = 0; k < 256; ++k)
        acc = fmaf(onorm[k], W_o[(size_t)k * 256 + j], acc);
    out[(size_t)n * 256 + j] = acc;
}

// ---------------------------------------------------------------------------
extern "C" void kernel_launch(void* const* d_in, const int* in_sizes, int n_in,
                              void* d_out, int out_size, void* d_ws, size_t ws_size,
                              hipStream_t stream)
{
    const float* query    = (const float*)d_in[0];   // (8,64,256)
    const float* keyval   = (const float*)d_in[1];   // (8,256,256)
    const int*   mask     = (const int*)  d_in[2];   // (8,256)
    const float* W_cond   = (const float*)d_in[3];   // (256,256)
    const float* W_q      = (const float*)d_in[4];   // (256,256)
    const float* W_k      = (const float*)d_in[5];   // (256,256)
    const float* W_v      = (const float*)d_in[6];   // (256,256)
    const float* W_gk1    = (const float*)d_in[7];   // (256,16)
    const float* W_gk2    = (const float*)d_in[8];   // (16,256)
    const float* b_gk2    = (const float*)d_in[9];   // (256,)
    const float* W_router = (const float*)d_in[10];  // (256,4)
    const float* norm_w   = (const float*)d_in[11];  // (64,)
    const float* W_o      = (const float*)d_in[12];  // (256,256)

    float* out    = (float*)d_out;        // (8,64,256)
    float* logits = out + Nn * Dd;        // (N*K, 4)

    // workspace layout (floats)
    float* p = (float*)d_ws;
    float* Wg    = p; p += 256 * 256;       // W_gk1 @ W_gk2
    float* KVb   = p; p += 2048 * SKV;      // keyval @ [k|v|p|r]
    float* cond  = p; p += Nn * 256;        // query @ W_cond
    float* qlast = p; p += 8 * 256;         // keyval[:,255,:] @ W_q
    float* Cb    = p; p += Nn * SCB;        // cond @ [q|k|v|p|r]

    // 1) Wg = W_gk1 @ W_gk2
    prep<<<256, dim3(256), 0, stream>>>(W_gk1, W_gk2, Wg);

    // 2) KVb + cond + qlast (242 blocks)
    gemm_main<<<242, dim3(256), 0, stream>>>(
        keyval, query, W_k, W_v, Wg, W_cond, W_q, W_router, KVb, cond, qlast);

    // 3) Cb = cond @ [q|k|v|p|r]  (72 blocks)
    gemm_cb<<<72, dim3(256), 0, stream>>>(cond, W_q, W_k, W_v, Wg, W_router, Cb);

    // 4) router + recurrence + RMSNorm + output projection
    mom_fused<<<Nn, dim3(256), 0, stream>>>(
        KVb, Cb, qlast, b_gk2, mask, W_o, norm_w, out, logits);
}